// Round 1
// baseline (212.212 us; speedup 1.0000x reference)
//
#include <hip/hip_runtime.h>

typedef unsigned short ushort_t;
using bf16x8 = __attribute__((ext_vector_type(8))) short;
using f32x4  = __attribute__((ext_vector_type(4))) float;

#define N_VOX 65536
#define KT 27
#define CH 64

__device__ inline unsigned short f2bf(float f) {
  unsigned int u = __builtin_bit_cast(unsigned int, f);
  u += 0x7fffu + ((u >> 16) & 1u);
  return (unsigned short)(u >> 16);
}

// ---- prep: fp32 -> bf16 convert of x ----
__global__ __launch_bounds__(256) void k_cvt_x(const float* __restrict__ x,
                                               ushort_t* __restrict__ xb) {
  int i = blockIdx.x * 256 + threadIdx.x;  // float4 index, total N*CH/4
  float4 v = ((const float4*)x)[i];
  ushort4 o;
  o.x = f2bf(v.x); o.y = f2bf(v.y); o.z = f2bf(v.z); o.w = f2bf(v.w);
  ((ushort4*)xb)[i] = o;
}

// ---- prep: W[k][c][d] fp32 -> Wt[k][d][c] bf16 (transposed so B-frag reads are contiguous) ----
__global__ __launch_bounds__(256) void k_cvt_w(const float* __restrict__ W,
                                               ushort_t* __restrict__ Wt) {
  int e = blockIdx.x * 256 + threadIdx.x;  // < 27*4096
  int k = e >> 12;
  int rem = e & 4095;
  int d = rem >> 6;
  int c = rem & 63;
  Wt[e] = f2bf(W[(k << 12) + (c << 6) + d]);
}

// ---- gather-GEMM conv via MFMA ----
// block = 256 thr = 4 waves; block owns 64 voxels; wave w owns voxels w*16..w*16+15,
// computes all 64 output channels with 4 16x16 accumulators.
__global__ __launch_bounds__(256) void k_conv(const ushort_t* __restrict__ xb,   // [N][64] bf16
                                              const int* __restrict__ nbr,      // [N][27]
                                              const ushort_t* __restrict__ Wt,  // [27][64(d)][64(c)] bf16
                                              float* __restrict__ hout) {       // [N][64] fp32
  __shared__ int nb[KT][64];
  __shared__ ushort_t As[64][72];  // pad 64->72: frag ds_read_b128 at <=2-way bank alias (free)
  __shared__ ushort_t Bs[64][72];
  const int t = threadIdx.x;
  const int base = blockIdx.x * 64;

  for (int e = t; e < KT * 64; e += 256) {
    int v = e / KT;
    int k = e - v * KT;
    nb[k][v] = nbr[(base + v) * KT + k];
  }

  f32x4 acc[4] = {{0.f,0.f,0.f,0.f},{0.f,0.f,0.f,0.f},{0.f,0.f,0.f,0.f},{0.f,0.f,0.f,0.f}};

  const int lane = t & 63;
  const int w = t >> 6;
  const int m = lane & 15;
  const int quad = lane >> 4;
  const int sv = t >> 3;          // staging voxel (0..31), +32 on pass 1
  const int sch = (t & 7) * 8;    // staging channel start (16B granules)

  __syncthreads();

  for (int k = 0; k < KT; ++k) {
    const ushort_t* wk = Wt + (k << 12);
#pragma unroll
    for (int p = 0; p < 2; ++p) {
      int v = sv + p * 32;
      // stage W tile (straight copy, coalesced 16B/lane)
      *(uint4*)(&Bs[v][sch]) = *(const uint4*)(wk + v * 64 + sch);
      // stage gathered, masked A tile
      int idx = nb[k][v];
      uint4 val = {0u, 0u, 0u, 0u};
      if (idx >= 0) val = *(const uint4*)(xb + idx * 64 + sch);
      *(uint4*)(&As[v][sch]) = val;
    }
    __syncthreads();

    // A frag: A[m][kk], lane holds kk = quad*8..+7 (+32 for 2nd K-step)
    bf16x8 a0 = *(const bf16x8*)(&As[w * 16 + m][quad * 8]);
    bf16x8 a1 = *(const bf16x8*)(&As[w * 16 + m][32 + quad * 8]);
#pragma unroll
    for (int nt = 0; nt < 4; ++nt) {
      // B frag: B[kk][n] supplied from Bs[n][kk] (Bs holds W^T), contiguous in kk
      bf16x8 b0 = *(const bf16x8*)(&Bs[nt * 16 + m][quad * 8]);
      bf16x8 b1 = *(const bf16x8*)(&Bs[nt * 16 + m][32 + quad * 8]);
      acc[nt] = __builtin_amdgcn_mfma_f32_16x16x32_bf16(a0, b0, acc[nt], 0, 0, 0);
      acc[nt] = __builtin_amdgcn_mfma_f32_16x16x32_bf16(a1, b1, acc[nt], 0, 0, 0);
    }
    __syncthreads();
  }

  // C/D layout: col = lane&15, row = quad*4 + reg
  const int orow = base + w * 16 + quad * 4;
#pragma unroll
  for (int nt = 0; nt < 4; ++nt)
#pragma unroll
    for (int r = 0; r < 4; ++r)
      hout[(orow + r) * 64 + nt * 16 + m] = acc[nt][r];
}

// ---- per-channel sum / sumsq over N rows ----
__global__ __launch_bounds__(256) void k_stats(const float* __restrict__ h,
                                               float* __restrict__ gsum,
                                               float* __restrict__ gsq) {
  __shared__ float ss[256], qq[256];
  const int t = threadIdx.x;
  const int c = t & 63;
  const int rg = t >> 6;
  float s = 0.f, q = 0.f;
  const int row0 = blockIdx.x * 256 + rg;
  for (int i = 0; i < 64; ++i) {
    float v = h[(row0 + i * 4) * 64 + c];
    s += v;
    q += v * v;
  }
  ss[t] = s; qq[t] = q;
  __syncthreads();
  if (t < 64) {
    s = ss[t] + ss[t + 64] + ss[t + 128] + ss[t + 192];
    q = qq[t] + qq[t + 64] + qq[t + 128] + qq[t + 192];
    atomicAdd(&gsum[t], s);
    atomicAdd(&gsq[t], q);
  }
}

// ---- finalize BN affine params ----
__global__ void k_bn_params(const float* __restrict__ gsum, const float* __restrict__ gsq,
                            const float* __restrict__ gamma, const float* __restrict__ beta,
                            float* __restrict__ scale, float* __restrict__ shift) {
  int c = threadIdx.x;  // blockDim = 64
  float mean = gsum[c] * (1.f / N_VOX);
  float var = gsq[c] * (1.f / N_VOX) - mean * mean;
  float rs = rsqrtf(var + 1e-5f);
  float sc = gamma[c] * rs;
  scale[c] = sc;
  shift[c] = beta[c] - mean * sc;
}

// ---- BN + ReLU + cast to bf16 (feeds conv2 gather) ----
__global__ __launch_bounds__(256) void k_bn_relu_bf16(const float* __restrict__ h,
                                                      const float* __restrict__ scale,
                                                      const float* __restrict__ shift,
                                                      ushort_t* __restrict__ ob) {
  __shared__ float sc[64], sh[64];
  int t = threadIdx.x;
  if (t < 64) { sc[t] = scale[t]; sh[t] = shift[t]; }
  __syncthreads();
  int i = blockIdx.x * 256 + t;  // float4 index
  int c0 = (i << 2) & 63;
  float4 v = ((const float4*)h)[i];
  ushort4 o;
  o.x = f2bf(fmaxf(0.f, v.x * sc[c0]     + sh[c0]));
  o.y = f2bf(fmaxf(0.f, v.y * sc[c0 + 1] + sh[c0 + 1]));
  o.z = f2bf(fmaxf(0.f, v.z * sc[c0 + 2] + sh[c0 + 2]));
  o.w = f2bf(fmaxf(0.f, v.w * sc[c0 + 3] + sh[c0 + 3]));
  ((ushort4*)ob)[i] = o;
}

// ---- BN2 + residual + ReLU, fp32 out ----
__global__ __launch_bounds__(256) void k_final(const float* __restrict__ h,
                                               const float* __restrict__ x,
                                               const float* __restrict__ scale,
                                               const float* __restrict__ shift,
                                               float* __restrict__ out) {
  __shared__ float sc[64], sh[64];
  int t = threadIdx.x;
  if (t < 64) { sc[t] = scale[t]; sh[t] = shift[t]; }
  __syncthreads();
  int i = blockIdx.x * 256 + t;
  int c0 = (i << 2) & 63;
  float4 v = ((const float4*)h)[i];
  float4 xv = ((const float4*)x)[i];
  float4 o;
  o.x = fmaxf(0.f, v.x * sc[c0]     + sh[c0]     + xv.x);
  o.y = fmaxf(0.f, v.y * sc[c0 + 1] + sh[c0 + 1] + xv.y);
  o.z = fmaxf(0.f, v.z * sc[c0 + 2] + sh[c0 + 2] + xv.z);
  o.w = fmaxf(0.f, v.w * sc[c0 + 3] + sh[c0 + 3] + xv.w);
  ((float4*)out)[i] = o;
}

extern "C" void kernel_launch(void* const* d_in, const int* in_sizes, int n_in,
                              void* d_out, int out_size, void* d_ws, size_t ws_size,
                              hipStream_t stream) {
  const float* x   = (const float*)d_in[0];
  const int*   nbr = (const int*)d_in[1];
  const float* W1  = (const float*)d_in[2];
  const float* g1  = (const float*)d_in[3];
  const float* b1  = (const float*)d_in[4];
  const float* W2  = (const float*)d_in[5];
  const float* g2  = (const float*)d_in[6];
  const float* b2  = (const float*)d_in[7];
  float* out = (float*)d_out;
  char* ws = (char*)d_ws;

  // workspace layout (bytes), all 256-aligned; total ~50.8 MB
  ushort_t* xb    = (ushort_t*)(ws);               // 8,388,608
  ushort_t* h1b   = (ushort_t*)(ws + 8388608);     // 8,388,608
  ushort_t* W1t   = (ushort_t*)(ws + 16777216);    // 221,184
  ushort_t* W2t   = (ushort_t*)(ws + 16998400);    // 221,184
  float*    h1raw = (float*)(ws + 17219584);       // 16,777,216
  float*    h2raw = (float*)(ws + 33996800);       // 16,777,216
  float*    statsp  = (float*)(ws + 50774016);     // 4 x 64 floats
  float*    paramsp = (float*)(ws + 50775040);     // 4 x 64 floats
  float *gsum1 = statsp, *gsq1 = statsp + 64, *gsum2 = statsp + 128, *gsq2 = statsp + 192;
  float *sc1 = paramsp, *sh1 = paramsp + 64, *sc2 = paramsp + 128, *sh2 = paramsp + 192;

  hipMemsetAsync(statsp, 0, 256 * sizeof(float), stream);

  k_cvt_x<<<4096, 256, 0, stream>>>(x, xb);
  k_cvt_w<<<432, 256, 0, stream>>>(W1, W1t);
  k_cvt_w<<<432, 256, 0, stream>>>(W2, W2t);

  k_conv<<<1024, 256, 0, stream>>>(xb, nbr, W1t, h1raw);
  k_stats<<<256, 256, 0, stream>>>(h1raw, gsum1, gsq1);
  k_bn_params<<<1, 64, 0, stream>>>(gsum1, gsq1, g1, b1, sc1, sh1);
  k_bn_relu_bf16<<<4096, 256, 0, stream>>>(h1raw, sc1, sh1, h1b);

  k_conv<<<1024, 256, 0, stream>>>(h1b, nbr, W2t, h2raw);
  k_stats<<<256, 256, 0, stream>>>(h2raw, gsum2, gsq2);
  k_bn_params<<<1, 64, 0, stream>>>(gsum2, gsq2, g2, b2, sc2, sh2);

  k_final<<<4096, 256, 0, stream>>>(h2raw, x, sc2, sh2, out);
}